// Round 10
// baseline (308.548 us; speedup 1.0000x reference)
//
#include <hip/hip_runtime.h>
#include <hip/hip_bf16.h>

#define MDIM 4096      // B*S tokens
#define DDIM 512
#define HHEADS 8
#define SLEN 2048
#define TDIM 256
#define SPLIT 4
#define LDT 66
#define LDA 66         // attn LDS stride: 33 dwords -> conflict-free
#define EXPC 0.1803368801111244f   // 0.125 * log2(e)

typedef __attribute__((ext_vector_type(8))) short short8;
typedef __attribute__((ext_vector_type(16))) float f32x16;

__device__ __forceinline__ unsigned short f2bf(float f) {
    union { __hip_bfloat16 h; unsigned short u; } c;
    c.h = __float2bfloat16(f);
    return c.u;
}
__device__ __forceinline__ float bf2f(short s) {
    return __uint_as_float((unsigned)(unsigned short)s << 16);
}

// ---------------------------------------------------------------------------
// prep (R5, coalesced both ways): LDS-tiled 64x64 transposes.
// ---------------------------------------------------------------------------
__global__ __launch_bounds__(256) void prep_k(
    const float* __restrict__ Wq, const float* __restrict__ Wk, const float* __restrict__ Wv,
    const float* __restrict__ Wo, const float* __restrict__ W1, const float* __restrict__ W2,
    const float* __restrict__ Wp, const float* __restrict__ x,
    short* __restrict__ Wqt, short* __restrict__ Wkt, short* __restrict__ Wvt,
    short* __restrict__ Wot, short* __restrict__ W1t, short* __restrict__ W2t,
    short* __restrict__ Wpt, short* __restrict__ xbf)
{
    __shared__ short T[64][72];
    const int b = blockIdx.x, tid = threadIdx.x;

    if (b >= 800) {
        const int idx = (b - 800) * 256 + tid;
        for (int e = idx; e < 262144; e += 65536) {
            float4 f0 = *(const float4*)&x[e * 8];
            float4 f1 = *(const float4*)&x[e * 8 + 4];
            short8 o;
            o[0] = (short)f2bf(f0.x); o[1] = (short)f2bf(f0.y);
            o[2] = (short)f2bf(f0.z); o[3] = (short)f2bf(f0.w);
            o[4] = (short)f2bf(f1.x); o[5] = (short)f2bf(f1.y);
            o[6] = (short)f2bf(f1.z); o[7] = (short)f2bf(f1.w);
            *(short8*)&xbf[e * 8] = o;
        }
        return;
    }

    const float* srcp; short* dstp; int ss;
    if (b < 384) {
        int w = b >> 7, t = b & 127;
        int lh = t >> 3, kt0 = (t & 7) << 6;
        const float* W = (w == 0) ? Wq : (w == 1) ? Wk : Wv;
        short* Wt = (w == 0) ? Wqt : (w == 1) ? Wkt : Wvt;
        srcp = W + (size_t)lh * 32768 + (size_t)kt0 * 64;
        dstp = Wt + (size_t)lh * 32768 + kt0;
        ss = 64;
    } else if (b < 768) {
        int w = (b - 384) >> 7, t = (b - 384) & 127;
        int l = t >> 6, tt = t & 63;
        int kt0 = (tt >> 3) << 6, nt0 = (tt & 7) << 6;
        const float* W = (w == 0) ? Wo : (w == 1) ? W1 : W2;
        short* Wt = (w == 0) ? Wot : (w == 1) ? W1t : W2t;
        srcp = W + (size_t)l * 262144 + (size_t)kt0 * 512 + nt0;
        dstp = Wt + (size_t)l * 262144 + (size_t)nt0 * 512 + kt0;
        ss = 512;
    } else {
        int t = b - 768;
        int kt0 = (t >> 2) << 6, nt0 = (t & 3) << 6;
        srcp = Wp + (size_t)kt0 * 256 + nt0;
        dstp = Wpt + (size_t)nt0 * 512 + kt0;
        ss = 256;
    }

    const int r = tid >> 2, c0 = (tid & 3) * 16;
#pragma unroll
    for (int j = 0; j < 16; j += 4) {
        float4 f = *(const float4*)&srcp[(size_t)r * ss + c0 + j];
        T[r][c0 + j + 0] = (short)f2bf(f.x);
        T[r][c0 + j + 1] = (short)f2bf(f.y);
        T[r][c0 + j + 2] = (short)f2bf(f.z);
        T[r][c0 + j + 3] = (short)f2bf(f.w);
    }
    __syncthreads();
    short8 o0, o1;
#pragma unroll
    for (int j = 0; j < 8; ++j) { o0[j] = T[c0 + j][r]; o1[j] = T[c0 + 8 + j][r]; }
    *(short8*)&dstp[(size_t)r * 512 + c0] = o0;
    *(short8*)&dstp[(size_t)r * 512 + c0 + 8] = o1;
}

// ---------------------------------------------------------------------------
// bf16 MFMA GEMM (verbatim R7, proven): C[M,N] = A[M,K] @ B + bias.
// Bt[n][k]. Tile 64m x 64n, BK=64, 4 waves (2m x 2n).
// flags: 1=relu, 2=bf16 out.
// ---------------------------------------------------------------------------
__global__ __launch_bounds__(256, 2) void gemm_bf(
    const short* __restrict__ A, const short* __restrict__ Bt,
    const float* __restrict__ bias, void* __restrict__ Cout,
    int M, int N, int K, int flags)
{
    __shared__ short As[64 * LDT];
    __shared__ short Bs[64 * LDT];
    const int tid = threadIdx.x;
    const int wave = tid >> 6, lane = tid & 63;
    const int l31 = lane & 31, hi = lane >> 5;
    const int wm = wave >> 1, wn = wave & 1;
    const int m0 = blockIdx.y * 64, n0 = blockIdx.x * 64;

    f32x16 acc;
#pragma unroll
    for (int r = 0; r < 16; ++r) acc[r] = 0.f;

    const int sr = tid >> 2;          // 0..63
    const int sc = (tid & 3) * 16;    // short chunk

    for (int k0 = 0; k0 < K; k0 += 64) {
        __syncthreads();
        *(short8*)&As[sr * LDT + sc]     = *(const short8*)&A[(size_t)(m0 + sr) * K + k0 + sc];
        *(short8*)&As[sr * LDT + sc + 8] = *(const short8*)&A[(size_t)(m0 + sr) * K + k0 + sc + 8];
        *(short8*)&Bs[sr * LDT + sc]     = *(const short8*)&Bt[(size_t)(n0 + sr) * K + k0 + sc];
        *(short8*)&Bs[sr * LDT + sc + 8] = *(const short8*)&Bt[(size_t)(n0 + sr) * K + k0 + sc + 8];
        __syncthreads();

        short8 af[4], bfm[4];
#pragma unroll
        for (int ks = 0; ks < 4; ++ks) {
            af[ks]  = *(const short8*)&As[(wm * 32 + l31) * LDT + ks * 16 + hi * 8];
            bfm[ks] = *(const short8*)&Bs[(wn * 32 + l31) * LDT + ks * 16 + hi * 8];
        }
#pragma unroll
        for (int ks = 0; ks < 4; ++ks)
            acc = __builtin_amdgcn_mfma_f32_32x32x16_bf16(af[ks], bfm[ks], acc, 0, 0, 0);
    }

    const int col = n0 + wn * 32 + l31;
    const float bb = bias[col];
    const int rbase = m0 + wm * 32 + 4 * hi;
#pragma unroll
    for (int r = 0; r < 16; ++r) {
        int row = rbase + (r & 3) + 8 * (r >> 2);
        float v = acc[r] + bb;
        if (flags & 1) v = fmaxf(v, 0.f);
        if (flags & 2) ((short*)Cout)[(size_t)row * N + col] = (short)f2bf(v);
        else           ((float*)Cout)[(size_t)row * N + col] = v;
    }
}

// ---------------------------------------------------------------------------
// Wo GEMM with FUSED merge: A[m][k] is built on the fly from the 4 key-split
// partials (Opart) + l sums (lpart). K-chunks are head-aligned (h = k0/64),
// so the A-tile for chunk k0 is sum_sp Opart[sp*16+bh][s][d] * (1/sum_sp l).
// Numerics identical to the old merge_k (fp32 sum of bf16, *inv, f2bf).
// Deletes merge_k + the hcbf round-trip. Output y fp32, M=4096,N=512,K=512.
// ---------------------------------------------------------------------------
__global__ __launch_bounds__(256, 2) void gemm_wo(
    const short* __restrict__ Op, const float* __restrict__ lp,
    const short* __restrict__ Bt, const float* __restrict__ bias,
    float* __restrict__ Cout)
{
    __shared__ short As[64 * LDT];
    __shared__ short Bs[64 * LDT];
    const int tid = threadIdx.x;
    const int wave = tid >> 6, lane = tid & 63;
    const int l31 = lane & 31, hi = lane >> 5;
    const int wm = wave >> 1, wn = wave & 1;
    const int m0 = blockIdx.y * 64, n0 = blockIdx.x * 64;

    f32x16 acc;
#pragma unroll
    for (int r = 0; r < 16; ++r) acc[r] = 0.f;

    const int sr = tid >> 2;          // 0..63: A row within tile
    const int sc = (tid & 3) * 16;    // 16-short chunk within head
    const int t = m0 + sr;            // token
    const int b = t >> 11, s = t & (SLEN - 1);

    for (int k0 = 0; k0 < 512; k0 += 64) {
        const int h = k0 >> 6;                 // head for this K-chunk
        const int bh = b * HHEADS + h;

        // l sum for this row/head (4 loads; L2-resident)
        float ls = 0.f;
#pragma unroll
        for (int sp = 0; sp < SPLIT; ++sp)
            ls += lp[((size_t)(sp * 16 + bh)) * SLEN + s];
        const float inv = 1.f / ls;

        __syncthreads();
        // fused-merge A staging: o = sum_sp bf16(Opart), As = f2bf(o*inv)
        float o[16];
#pragma unroll
        for (int j = 0; j < 16; ++j) o[j] = 0.f;
#pragma unroll
        for (int sp = 0; sp < SPLIT; ++sp) {
            const size_t base = (((size_t)(sp * 16 + bh)) * SLEN + s) * 64 + sc;
            short8 u0 = *(const short8*)&Op[base];
            short8 u1 = *(const short8*)&Op[base + 8];
#pragma unroll
            for (int j = 0; j < 8; ++j) {
                o[j]     += bf2f(u0[j]);
                o[8 + j] += bf2f(u1[j]);
            }
        }
        short8 a0, a1;
#pragma unroll
        for (int j = 0; j < 8; ++j) {
            a0[j] = (short)f2bf(o[j] * inv);
            a1[j] = (short)f2bf(o[8 + j] * inv);
        }
        *(short8*)&As[sr * LDT + sc]     = a0;
        *(short8*)&As[sr * LDT + sc + 8] = a1;
        *(short8*)&Bs[sr * LDT + sc]     = *(const short8*)&Bt[(size_t)(n0 + sr) * 512 + k0 + sc];
        *(short8*)&Bs[sr * LDT + sc + 8] = *(const short8*)&Bt[(size_t)(n0 + sr) * 512 + k0 + sc + 8];
        __syncthreads();

        short8 af[4], bfm[4];
#pragma unroll
        for (int ks = 0; ks < 4; ++ks) {
            af[ks]  = *(const short8*)&As[(wm * 32 + l31) * LDT + ks * 16 + hi * 8];
            bfm[ks] = *(const short8*)&Bs[(wn * 32 + l31) * LDT + ks * 16 + hi * 8];
        }
#pragma unroll
        for (int ks = 0; ks < 4; ++ks)
            acc = __builtin_amdgcn_mfma_f32_32x32x16_bf16(af[ks], bfm[ks], acc, 0, 0, 0);
    }

    const int col = n0 + wn * 32 + l31;
    const float bb = bias[col];
    const int rbase = m0 + wm * 32 + 4 * hi;
#pragma unroll
    for (int r = 0; r < 16; ++r) {
        int row = rbase + (r & 3) + 8 * (r >> 2);
        Cout[(size_t)row * 512 + col] = acc[r] + bb;
    }
}

// ---------------------------------------------------------------------------
// Fused QKV MFMA GEMM (verbatim R1/R7): A=xbf [4096,512]; grid (24, 32).
// ---------------------------------------------------------------------------
__global__ __launch_bounds__(256, 2) void qkv_bf(
    const short* __restrict__ A,
    const short* __restrict__ Wqt, const short* __restrict__ Wkt, const short* __restrict__ Wvt,
    const float* __restrict__ bq, const float* __restrict__ bk, const float* __restrict__ bv,
    short* __restrict__ Oq, short* __restrict__ Ok, short* __restrict__ Ov)
{
    __shared__ short As[128 * LDT];
    __shared__ short Bs[64 * LDT];
    const int tid = threadIdx.x;
    const int wave = tid >> 6, lane = tid & 63;
    const int l31 = lane & 31, hi = lane >> 5;
    const int wm = wave >> 1, wn = wave & 1;
    const int m0 = blockIdx.y * 128;
    const int nt = blockIdx.x;
    const int which = nt >> 3, h = nt & 7;

    const short* Bt = ((which == 0) ? Wqt : (which == 1) ? Wkt : Wvt) + (size_t)h * 64 * 512;
    const float* bias = ((which == 0) ? bq : (which == 1) ? bk : bv) + h * 64;
    short* Out = (which == 0) ? Oq : (which == 1) ? Ok : Ov;

    f32x16 acc[2];
#pragma unroll
    for (int ms = 0; ms < 2; ++ms)
#pragma unroll
        for (int r = 0; r < 16; ++r) acc[ms][r] = 0.f;

    const int sr = tid >> 3;
    const int sc = (tid & 7) * 8;

    for (int k0 = 0; k0 < 512; k0 += 64) {
        __syncthreads();
#pragma unroll
        for (int p = 0; p < 4; ++p)
            *(short8*)&As[(p * 32 + sr) * LDT + sc] =
                *(const short8*)&A[(size_t)(m0 + p * 32 + sr) * 512 + k0 + sc];
#pragma unroll
        for (int p = 0; p < 2; ++p)
            *(short8*)&Bs[(p * 32 + sr) * LDT + sc] =
                *(const short8*)&Bt[(size_t)(p * 32 + sr) * 512 + k0 + sc];
        __syncthreads();

        short8 af[2][4], bfm[4];
#pragma unroll
        for (int ms = 0; ms < 2; ++ms)
#pragma unroll
            for (int ks = 0; ks < 4; ++ks)
                af[ms][ks] = *(const short8*)&As[(wm * 64 + ms * 32 + l31) * LDT + ks * 16 + hi * 8];
#pragma unroll
        for (int ks = 0; ks < 4; ++ks)
            bfm[ks] = *(const short8*)&Bs[(wn * 32 + l31) * LDT + ks * 16 + hi * 8];
#pragma unroll
        for (int ms = 0; ms < 2; ++ms)
#pragma unroll
            for (int ks = 0; ks < 4; ++ks)
                acc[ms] = __builtin_amdgcn_mfma_f32_32x32x16_bf16(af[ms][ks], bfm[ks], acc[ms], 0, 0, 0);
    }

    const int a = wn * 32 + l31;
    const float bb = bias[a];
    const int b = m0 >> 11;
    const int sb = (m0 & (SLEN - 1)) + wm * 64;
    const int bh = b * HHEADS + h;

    if (which == 0) {
        short* Ob = Out + (size_t)bh * SLEN * 64;
#pragma unroll
        for (int ms = 0; ms < 2; ++ms)
#pragma unroll
            for (int r = 0; r < 16; ++r) {
                int s = sb + ms * 32 + (r & 3) + 8 * (r >> 2) + 4 * hi;
                Ob[(size_t)s * 64 + a] = (short)f2bf((acc[ms][r] + bb) * EXPC);
            }
    } else if (which == 1) {
        short* Ob = Out + (size_t)bh * SLEN * 64;
#pragma unroll
        for (int ms = 0; ms < 2; ++ms)
#pragma unroll
            for (int r = 0; r < 16; ++r) {
                int s = sb + ms * 32 + (r & 3) + 8 * (r >> 2) + 4 * hi;
                Ob[(size_t)s * 64 + a] = (short)f2bf(acc[ms][r] + bb);
            }
    } else {
        short* Ob = Out + ((size_t)bh * 64 + a) * SLEN;
#pragma unroll
        for (int ms = 0; ms < 2; ++ms)
#pragma unroll
            for (int g = 0; g < 4; ++g) {
                int s = sb + ms * 32 + 8 * g + 4 * hi;
                ushort4 w;
                w.x = f2bf(acc[ms][4 * g + 0] + bb);
                w.y = f2bf(acc[ms][4 * g + 1] + bb);
                w.z = f2bf(acc[ms][4 * g + 2] + bb);
                w.w = f2bf(acc[ms][4 * g + 3] + bb);
                *(ushort4*)&Ob[s] = w;
            }
    }
}

// ---------------------------------------------------------------------------
// attn (verbatim R7: grid (8,16,4), q-heavy 256q x 512k, LDA=66 conflict-free,
// single LDS buffer + reg prefetch; R9's explicit dbuf was neutral).
// ---------------------------------------------------------------------------
__global__ __launch_bounds__(256, 2) void attn_mfma(
    const short* __restrict__ Qb, const short* __restrict__ Kb,
    const short* __restrict__ Vtb, short* __restrict__ Op,
    float* __restrict__ lp)
{
    __shared__ short Ks[64 * LDA];
    __shared__ short Vs[64 * LDA];

    const int tid = threadIdx.x;
    const int wid = tid >> 6;
    const int lane = tid & 63;
    const int l31 = lane & 31;
    const int hi = lane >> 5;

    const int qt = blockIdx.x;
    const int bh = blockIdx.y;
    const int sp = blockIdx.z;

    const short* Qg = Qb + (size_t)bh * SLEN * 64;
    const short* Kg = Kb + (size_t)bh * SLEN * 64;
    const short* Vg = Vtb + (size_t)bh * 64 * SLEN;

    const int q0 = qt * 256 + wid * 64;

    short8 qf[2][4];
#pragma unroll
    for (int nt = 0; nt < 2; ++nt)
#pragma unroll
        for (int ks = 0; ks < 4; ++ks)
            qf[nt][ks] = *(const short8*)&Qg[(size_t)(q0 + nt * 32 + l31) * 64 + ks * 16 + hi * 8];

    f32x16 oacc[2][2];
    float lsum[2] = {0.f, 0.f};
#pragma unroll
    for (int nt = 0; nt < 2; ++nt)
#pragma unroll
        for (int dt = 0; dt < 2; ++dt)
#pragma unroll
            for (int r = 0; r < 16; ++r) oacc[nt][dt][r] = 0.f;

    const int srow = tid >> 2;
    const int sch = (tid & 3) * 16;
    const int kbase = sp * (SLEN / SPLIT);

    // prologue: stage tile 0 into registers
    short8 rk0 = *(const short8*)&Kg[(size_t)(kbase + srow) * 64 + sch];
    short8 rk1 = *(const short8*)&Kg[(size_t)(kbase + srow) * 64 + sch + 8];
    short8 rv0 = *(const short8*)&Vg[(size_t)srow * SLEN + kbase + sch];
    short8 rv1 = *(const short8*)&Vg[(size_t)srow * SLEN + kbase + sch + 8];

#pragma unroll 1
    for (int kt = 0; kt < 8; ++kt) {
        __syncthreads();
        *(short8*)&Ks[srow * LDA + sch]     = rk0;
        *(short8*)&Ks[srow * LDA + sch + 8] = rk1;
        *(short8*)&Vs[srow * LDA + sch]     = rv0;
        *(short8*)&Vs[srow * LDA + sch + 8] = rv1;
        __syncthreads();

        if (kt < 7) {
            const int k0n = kbase + (kt + 1) * 64;
            rk0 = *(const short8*)&Kg[(size_t)(k0n + srow) * 64 + sch];
            rk1 = *(const short8*)&Kg[(size_t)(k0n + srow) * 64 + sch + 8];
            rv0 = *(const short8*)&Vg[(size_t)srow * SLEN + k0n + sch];
            rv1 = *(const short8*)&Vg[(size_t)srow * SLEN + k0n + sch + 8];
        }

        short8 kf[2][4], vf[2][4];
#pragma unroll
        for (int mt = 0; mt < 2; ++mt)
#pragma unroll
            for (int ks = 0; ks < 4; ++ks)
                kf[mt][ks] = *(const short8*)&Ks[(mt * 32 + l31) * LDA + ks * 16 + hi * 8];
#pragma unroll
        for (int dt = 0; dt < 2; ++dt)
#pragma unroll
            for (int p = 0; p < 4; ++p)
                vf[dt][p] = *(const short8*)&Vs[(dt * 32 + l31) * LDA + p * 16 + hi * 8];

#pragma unroll
        for (int nt = 0; nt < 2; ++nt) {
            f32x16 sacc[2];
            __builtin_amdgcn_s_setprio(1);
#pragma unroll
            for (int mt = 0; mt < 2; ++mt) {
                f32x16 s;
#pragma unroll
                for (int r = 0; r < 16; ++r) s[r] = 0.f;
#pragma unroll
                for (int ks = 0; ks < 4; ++ks)
                    s = __builtin_amdgcn_mfma_f32_32x32x16_bf16(kf[mt][ks], qf[nt][ks], s, 0, 0, 0);
                sacc[mt] = s;
            }
            __builtin_amdgcn_s_setprio(0);

            // p = exp2(s); pack via v_perm truncation; VALU lsum on the SAME
            // truncated values (numerator/denominator rounding matched).
            int2 pk[2][4];
#pragma unroll
            for (int mt = 0; mt < 2; ++mt)
#pragma unroll
                for (int g = 0; g < 4; ++g) {
                    unsigned a0 = __float_as_uint(__builtin_amdgcn_exp2f(sacc[mt][4 * g + 0]));
                    unsigned a1 = __float_as_uint(__builtin_amdgcn_exp2f(sacc[mt][4 * g + 1]));
                    unsigned a2 = __float_as_uint(__builtin_amdgcn_exp2f(sacc[mt][4 * g + 2]));
                    unsigned a3 = __float_as_uint(__builtin_amdgcn_exp2f(sacc[mt][4 * g + 3]));
                    float t0 = __uint_as_float(a0 & 0xffff0000u);
                    float t1 = __uint_as_float(a1 & 0xffff0000u);
                    float t2 = __uint_as_float(a2 & 0xffff0000u);
                    float t3 = __uint_as_float(a3 & 0xffff0000u);
                    lsum[nt] += (t0 + t1) + (t2 + t3);
                    pk[mt][g].x = (int)__builtin_amdgcn_perm(a1, a0, 0x07060302u);
                    pk[mt][g].y = (int)__builtin_amdgcn_perm(a3, a2, 0x07060302u);
                }

            int2 xch[2][2];
#pragma unroll
            for (int mt = 0; mt < 2; ++mt)
#pragma unroll
                for (int h2 = 0; h2 < 2; ++h2) {
                    int2 v = hi ? pk[mt][2 * h2] : pk[mt][2 * h2 + 1];
                    xch[mt][h2].x = __shfl_xor(v.x, 32);
                    xch[mt][h2].y = __shfl_xor(v.y, 32);
                }

            __builtin_amdgcn_s_setprio(1);
#pragma unroll
            for (int p = 0; p < 4; ++p) {
                const int mt = p >> 1, h2 = p & 1;
                const int ga = 2 * h2, gb = 2 * h2 + 1;
                const int2 X = xch[mt][h2];
                union { int4 i; short8 s; } u;
                u.i.x = hi ? X.x : pk[mt][ga].x;
                u.i.y = hi ? X.y : pk[mt][ga].y;
                u.i.z = hi ? pk[mt][gb].x : X.x;
                u.i.w = hi ? pk[mt][gb].y : X.y;
#pragma unroll
                for (int dt = 0; dt < 2; ++dt)
                    oacc[nt][dt] = __builtin_amdgcn_mfma_f32_32x32x16_bf16(u.s, vf[dt][p], oacc[nt][dt], 0, 0, 0);
            }
            __builtin_amdgcn_s_setprio(0);
        }
    }

#pragma unroll
    for (int nt = 0; nt < 2; ++nt) {
        float lt = lsum[nt] + __shfl_xor(lsum[nt], 32);
        if (hi == 0)
            lp[((size_t)(sp * 16 + bh)) * SLEN + q0 + nt * 32 + l31] = lt;
#pragma unroll
        for (int dt = 0; dt < 2; ++dt) {
#pragma unroll
            for (int r = 0; r < 16; ++r) {
                int qrow = (r & 3) + 8 * (r >> 2) + 4 * hi;
                size_t addr = (((size_t)(sp * 16 + bh)) * SLEN + (q0 + nt * 32 + qrow)) * 64 + dt * 32 + l31;
                Op[addr] = (short)f2bf(oacc[nt][dt][r]);
            }
        }
    }
}

// ---------------------------------------------------------------------------
// AddNorm on bf16 stream (verbatim R1): xbf = LN(xbf + y) * g + b ; y fp32.
// ---------------------------------------------------------------------------
__global__ __launch_bounds__(256) void addnorm_bf(
    short* __restrict__ X, const float* __restrict__ Y,
    const float* __restrict__ g, const float* __restrict__ beta)
{
    const int lane = threadIdx.x & 63;
    const int t = blockIdx.x * 4 + (threadIdx.x >> 6);
    short* xr = X + (size_t)t * DDIM;
    const float* yr = Y + (size_t)t * DDIM;
    const int c0 = lane * 8;

    short8 x8 = *(const short8*)&xr[c0];
    float4 y0 = *(const float4*)&yr[c0];
    float4 y1 = *(const float4*)&yr[c0 + 4];
    float v[8];
    v[0] = bf2f(x8[0]) + y0.x; v[1] = bf2f(x8[1]) + y0.y;
    v[2] = bf2f(x8[2]) + y0.z; v[3] = bf2f(x8[3]) + y0.w;
    v[4] = bf2f(x8[4]) + y1.x; v[5] = bf2f(x8[5]) + y1.y;
    v[6] = bf2f(x8[6]) + y1.z; v[7] = bf2f(x8[7]) + y1.w;

    float s1 = 0.f, s2 = 0.f;
#pragma unroll
    for (int j = 0; j < 8; ++j) { s1 += v[j]; s2 += v[j] * v[j]; }
#pragma unroll
    for (int off = 1; off < 64; off <<= 1) {
        s1 += __shfl_xor(s1, off);
        s2 += __shfl_xor(s2, off);
    }
    float mean = s1 * (1.0f / DDIM);
    float var = s2 * (1.0f / DDIM) - mean * mean;
    float rstd = rsqrtf(var + 1e-5f);

    float4 ga = *(const float4*)&g[c0];
    float4 gb = *(const float4*)&g[c0 + 4];
    float4 ba = *(const float4*)&beta[c0];
    float4 bb = *(const float4*)&beta[c0 + 4];
    float gg[8] = {ga.x, ga.y, ga.z, ga.w, gb.x, gb.y, gb.z, gb.w};
    float bt[8] = {ba.x, ba.y, ba.z, ba.w, bb.x, bb.y, bb.z, bb.w};

    short8 o8;
#pragma unroll
    for (int j = 0; j < 8; ++j)
        o8[j] = (short)f2bf((v[j] - mean) * rstd * gg[j] + bt[j]);
    *(short8*)&xr[c0] = o8;
}

// ---------------------------------------------------------------------------
// Workspace (MiB), overlays lifetime-checked (merge-fused layout):
//   [ 0, 4)  xbf                 (alive whole run)
//   [ 4,12)  Qbuf[4,8)+Kbuf[8,12) | y fp32 (Q/K dead after attn; y produced
//                                  by gemm_wo AFTER attn, dead after addnorm)
//   [12,16)  Vtbuf
//   [16,32)  Opart (attn -> gemm_wo) | hidbf [24,28) (after Wo done)
//   [32,32.5) lpart
//   [33,39.25) weights bf16
// ---------------------------------------------------------------------------
extern "C" void kernel_launch(void* const* d_in, const int* in_sizes, int n_in,
                              void* d_out, int out_size, void* d_ws, size_t ws_size,
                              hipStream_t stream)
{
    (void)in_sizes; (void)n_in; (void)out_size; (void)ws_size;
    const float* x   = (const float*)d_in[0];
    const float* Wq  = (const float*)d_in[1];
    const float* bq  = (const float*)d_in[2];
    const float* Wk  = (const float*)d_in[3];
    const float* bk  = (const float*)d_in[4];
    const float* Wv  = (const float*)d_in[5];
    const float* bv  = (const float*)d_in[6];
    const float* Wo  = (const float*)d_in[7];
    const float* bo  = (const float*)d_in[8];
    const float* g1  = (const float*)d_in[9];
    const float* be1 = (const float*)d_in[10];
    const float* W1  = (const float*)d_in[11];
    const float* b1  = (const float*)d_in[12];
    const float* W2  = (const float*)d_in[13];
    const float* b2  = (const float*)d_in[14];
    const float* g2  = (const float*)d_in[15];
    const float* be2 = (const float*)d_in[16];
    const float* Wp  = (const float*)d_in[17];
    const float* bp  = (const float*)d_in[18];

    char* wsb = (char*)d_ws;
    const size_t MB = 1024 * 1024;
    short* xbf   = (short*)(wsb + 0);
    short* Qbuf  = (short*)(wsb + 4 * MB);
    short* Kbuf  = (short*)(wsb + 8 * MB);
    short* Vtbuf = (short*)(wsb + 12 * MB);
    float* y     = (float*)(wsb + 4 * MB);    // overlay Q/K (disjoint lifetime)
    short* Opart = (short*)(wsb + 16 * MB);
    short* hidbf = (short*)(wsb + 24 * MB);   // overlay Opart tail (Wo done)
    float* lpart = (float*)(wsb + 32 * MB);
    short* Wqt   = (short*)(wsb + 33 * MB);
    short* Wkt   = (short*)(wsb + 34 * MB);
    short* Wvt   = (short*)(wsb + 35 * MB);
    short* Wot   = (short*)(wsb + 36 * MB);
    short* W1t   = (short*)(wsb + 37 * MB);
    short* W2t   = (short*)(wsb + 38 * MB);
    short* Wpt   = (short*)(wsb + 39 * MB);

    prep_k<<<1056, 256, 0, stream>>>(Wq, Wk, Wv, Wo, W1, W2, Wp, x,
                                     Wqt, Wkt, Wvt, Wot, W1t, W2t, Wpt, xbf);

    for (int i = 0; i < 2; ++i) {
        const size_t wOff = (size_t)i * 262144;
        qkv_bf<<<dim3(24, 32), 256, 0, stream>>>(
            xbf, Wqt + wOff, Wkt + wOff, Wvt + wOff,
            bq + i * 512, bk + i * 512, bv + i * 512,
            Qbuf, Kbuf, Vtbuf);
        attn_mfma<<<dim3(8, 16, SPLIT), 256, 0, stream>>>(Qbuf, Kbuf, Vtbuf, Opart, lpart);
        gemm_wo<<<dim3(8, 64), 256, 0, stream>>>(
            Opart, lpart, Wot + wOff, bo + i * 512, y);
        addnorm_bf<<<1024, 256, 0, stream>>>(xbf, y, g1 + i * 512, be1 + i * 512);
        gemm_bf<<<dim3(8, 64), 256, 0, stream>>>(
            xbf, W1t + wOff, b1 + i * 512, hidbf, MDIM, DDIM, DDIM, 3);
        gemm_bf<<<dim3(8, 64), 256, 0, stream>>>(
            hidbf, W2t + wOff, b2 + i * 512, y, MDIM, DDIM, DDIM, 0);
        addnorm_bf<<<1024, 256, 0, stream>>>(xbf, y, g2 + i * 512, be2 + i * 512);
    }
    gemm_bf<<<dim3(4, 64), 256, 0, stream>>>(
        xbf, Wpt, bp, (float*)d_out, MDIM, TDIM, DDIM, 0);
}

// Round 11
// 283.562 us; speedup vs baseline: 1.0881x; 1.0881x over previous
//
#include <hip/hip_runtime.h>
#include <hip/hip_bf16.h>

#define MDIM 4096      // B*S tokens
#define DDIM 512
#define HHEADS 8
#define SLEN 2048
#define TDIM 256
#define SPLIT 4
#define LDT 66
#define LDA 66         // attn LDS stride: 33 dwords -> bank = l31, conflict-free
#define EXPC 0.1803368801111244f   // 0.125 * log2(e)

typedef __attribute__((ext_vector_type(8))) short short8;
typedef __attribute__((ext_vector_type(16))) float f32x16;

__device__ __forceinline__ unsigned short f2bf(float f) {
    union { __hip_bfloat16 h; unsigned short u; } c;
    c.h = __float2bfloat16(f);
    return c.u;
}
__device__ __forceinline__ float bf2f(short s) {
    return __uint_as_float((unsigned)(unsigned short)s << 16);
}

// ---------------------------------------------------------------------------
// prep (R5, coalesced both ways): LDS-tiled 64x64 transposes.
// ---------------------------------------------------------------------------
__global__ __launch_bounds__(256) void prep_k(
    const float* __restrict__ Wq, const float* __restrict__ Wk, const float* __restrict__ Wv,
    const float* __restrict__ Wo, const float* __restrict__ W1, const float* __restrict__ W2,
    const float* __restrict__ Wp, const float* __restrict__ x,
    short* __restrict__ Wqt, short* __restrict__ Wkt, short* __restrict__ Wvt,
    short* __restrict__ Wot, short* __restrict__ W1t, short* __restrict__ W2t,
    short* __restrict__ Wpt, short* __restrict__ xbf)
{
    __shared__ short T[64][72];
    const int b = blockIdx.x, tid = threadIdx.x;

    if (b >= 800) {
        const int idx = (b - 800) * 256 + tid;
        for (int e = idx; e < 262144; e += 65536) {
            float4 f0 = *(const float4*)&x[e * 8];
            float4 f1 = *(const float4*)&x[e * 8 + 4];
            short8 o;
            o[0] = (short)f2bf(f0.x); o[1] = (short)f2bf(f0.y);
            o[2] = (short)f2bf(f0.z); o[3] = (short)f2bf(f0.w);
            o[4] = (short)f2bf(f1.x); o[5] = (short)f2bf(f1.y);
            o[6] = (short)f2bf(f1.z); o[7] = (short)f2bf(f1.w);
            *(short8*)&xbf[e * 8] = o;
        }
        return;
    }

    const float* srcp; short* dstp; int ss;
    if (b < 384) {
        int w = b >> 7, t = b & 127;
        int lh = t >> 3, kt0 = (t & 7) << 6;
        const float* W = (w == 0) ? Wq : (w == 1) ? Wk : Wv;
        short* Wt = (w == 0) ? Wqt : (w == 1) ? Wkt : Wvt;
        srcp = W + (size_t)lh * 32768 + (size_t)kt0 * 64;
        dstp = Wt + (size_t)lh * 32768 + kt0;
        ss = 64;
    } else if (b < 768) {
        int w = (b - 384) >> 7, t = (b - 384) & 127;
        int l = t >> 6, tt = t & 63;
        int kt0 = (tt >> 3) << 6, nt0 = (tt & 7) << 6;
        const float* W = (w == 0) ? Wo : (w == 1) ? W1 : W2;
        short* Wt = (w == 0) ? Wot : (w == 1) ? W1t : W2t;
        srcp = W + (size_t)l * 262144 + (size_t)kt0 * 512 + nt0;
        dstp = Wt + (size_t)l * 262144 + (size_t)nt0 * 512 + kt0;
        ss = 512;
    } else {
        int t = b - 768;
        int kt0 = (t >> 2) << 6, nt0 = (t & 3) << 6;
        srcp = Wp + (size_t)kt0 * 256 + nt0;
        dstp = Wpt + (size_t)nt0 * 512 + kt0;
        ss = 256;
    }

    const int r = tid >> 2, c0 = (tid & 3) * 16;
#pragma unroll
    for (int j = 0; j < 16; j += 4) {
        float4 f = *(const float4*)&srcp[(size_t)r * ss + c0 + j];
        T[r][c0 + j + 0] = (short)f2bf(f.x);
        T[r][c0 + j + 1] = (short)f2bf(f.y);
        T[r][c0 + j + 2] = (short)f2bf(f.z);
        T[r][c0 + j + 3] = (short)f2bf(f.w);
    }
    __syncthreads();
    short8 o0, o1;
#pragma unroll
    for (int j = 0; j < 8; ++j) { o0[j] = T[c0 + j][r]; o1[j] = T[c0 + 8 + j][r]; }
    *(short8*)&dstp[(size_t)r * 512 + c0] = o0;
    *(short8*)&dstp[(size_t)r * 512 + c0 + 8] = o1;
}

// ---------------------------------------------------------------------------
// bf16 MFMA GEMM (proven R0/R7): C[M,N] = A[M,K] @ B + bias.
// Bt[n][k]. Tile 64m x 64n, BK=64, 4 waves (2m x 2n).
// flags: 1=relu, 2=bf16 out.
// ---------------------------------------------------------------------------
__global__ __launch_bounds__(256, 2) void gemm_bf(
    const short* __restrict__ A, const short* __restrict__ Bt,
    const float* __restrict__ bias, void* __restrict__ Cout,
    int M, int N, int K, int flags)
{
    __shared__ short As[64 * LDT];
    __shared__ short Bs[64 * LDT];
    const int tid = threadIdx.x;
    const int wave = tid >> 6, lane = tid & 63;
    const int l31 = lane & 31, hi = lane >> 5;
    const int wm = wave >> 1, wn = wave & 1;
    const int m0 = blockIdx.y * 64, n0 = blockIdx.x * 64;

    f32x16 acc;
#pragma unroll
    for (int r = 0; r < 16; ++r) acc[r] = 0.f;

    const int sr = tid >> 2;          // 0..63
    const int sc = (tid & 3) * 16;    // short chunk

    for (int k0 = 0; k0 < K; k0 += 64) {
        __syncthreads();
        *(short8*)&As[sr * LDT + sc]     = *(const short8*)&A[(size_t)(m0 + sr) * K + k0 + sc];
        *(short8*)&As[sr * LDT + sc + 8] = *(const short8*)&A[(size_t)(m0 + sr) * K + k0 + sc + 8];
        *(short8*)&Bs[sr * LDT + sc]     = *(const short8*)&Bt[(size_t)(n0 + sr) * K + k0 + sc];
        *(short8*)&Bs[sr * LDT + sc + 8] = *(const short8*)&Bt[(size_t)(n0 + sr) * K + k0 + sc + 8];
        __syncthreads();

        short8 af[4], bfm[4];
#pragma unroll
        for (int ks = 0; ks < 4; ++ks) {
            af[ks]  = *(const short8*)&As[(wm * 32 + l31) * LDT + ks * 16 + hi * 8];
            bfm[ks] = *(const short8*)&Bs[(wn * 32 + l31) * LDT + ks * 16 + hi * 8];
        }
#pragma unroll
        for (int ks = 0; ks < 4; ++ks)
            acc = __builtin_amdgcn_mfma_f32_32x32x16_bf16(af[ks], bfm[ks], acc, 0, 0, 0);
    }

    const int col = n0 + wn * 32 + l31;
    const float bb = bias[col];
    const int rbase = m0 + wm * 32 + 4 * hi;
#pragma unroll
    for (int r = 0; r < 16; ++r) {
        int row = rbase + (r & 3) + 8 * (r >> 2);
        float v = acc[r] + bb;
        if (flags & 1) v = fmaxf(v, 0.f);
        if (flags & 2) ((short*)Cout)[(size_t)row * N + col] = (short)f2bf(v);
        else           ((float*)Cout)[(size_t)row * N + col] = v;
    }
}

// ---------------------------------------------------------------------------
// Fused QKV MFMA GEMM (verbatim R1/R7): A=xbf [4096,512]; grid (24, 32).
// Q pre-scaled by 0.125*log2(e); Q,K [bh][s][64] bf16; V transposed [bh][d][s].
// ---------------------------------------------------------------------------
__global__ __launch_bounds__(256, 2) void qkv_bf(
    const short* __restrict__ A,
    const short* __restrict__ Wqt, const short* __restrict__ Wkt, const short* __restrict__ Wvt,
    const float* __restrict__ bq, const float* __restrict__ bk, const float* __restrict__ bv,
    short* __restrict__ Oq, short* __restrict__ Ok, short* __restrict__ Ov)
{
    __shared__ short As[128 * LDT];
    __shared__ short Bs[64 * LDT];
    const int tid = threadIdx.x;
    const int wave = tid >> 6, lane = tid & 63;
    const int l31 = lane & 31, hi = lane >> 5;
    const int wm = wave >> 1, wn = wave & 1;
    const int m0 = blockIdx.y * 128;
    const int nt = blockIdx.x;
    const int which = nt >> 3, h = nt & 7;

    const short* Bt = ((which == 0) ? Wqt : (which == 1) ? Wkt : Wvt) + (size_t)h * 64 * 512;
    const float* bias = ((which == 0) ? bq : (which == 1) ? bk : bv) + h * 64;
    short* Out = (which == 0) ? Oq : (which == 1) ? Ok : Ov;

    f32x16 acc[2];
#pragma unroll
    for (int ms = 0; ms < 2; ++ms)
#pragma unroll
        for (int r = 0; r < 16; ++r) acc[ms][r] = 0.f;

    const int sr = tid >> 3;
    const int sc = (tid & 7) * 8;

    for (int k0 = 0; k0 < 512; k0 += 64) {
        __syncthreads();
#pragma unroll
        for (int p = 0; p < 4; ++p)
            *(short8*)&As[(p * 32 + sr) * LDT + sc] =
                *(const short8*)&A[(size_t)(m0 + p * 32 + sr) * 512 + k0 + sc];
#pragma unroll
        for (int p = 0; p < 2; ++p)
            *(short8*)&Bs[(p * 32 + sr) * LDT + sc] =
                *(const short8*)&Bt[(size_t)(p * 32 + sr) * 512 + k0 + sc];
        __syncthreads();

        short8 af[2][4], bfm[4];
#pragma unroll
        for (int ms = 0; ms < 2; ++ms)
#pragma unroll
            for (int ks = 0; ks < 4; ++ks)
                af[ms][ks] = *(const short8*)&As[(wm * 64 + ms * 32 + l31) * LDT + ks * 16 + hi * 8];
#pragma unroll
        for (int ks = 0; ks < 4; ++ks)
            bfm[ks] = *(const short8*)&Bs[(wn * 32 + l31) * LDT + ks * 16 + hi * 8];
#pragma unroll
        for (int ms = 0; ms < 2; ++ms)
#pragma unroll
            for (int ks = 0; ks < 4; ++ks)
                acc[ms] = __builtin_amdgcn_mfma_f32_32x32x16_bf16(af[ms][ks], bfm[ks], acc[ms], 0, 0, 0);
    }

    const int a = wn * 32 + l31;
    const float bb = bias[a];
    const int b = m0 >> 11;
    const int sb = (m0 & (SLEN - 1)) + wm * 64;
    const int bh = b * HHEADS + h;

    if (which == 0) {
        short* Ob = Out + (size_t)bh * SLEN * 64;
#pragma unroll
        for (int ms = 0; ms < 2; ++ms)
#pragma unroll
            for (int r = 0; r < 16; ++r) {
                int s = sb + ms * 32 + (r & 3) + 8 * (r >> 2) + 4 * hi;
                Ob[(size_t)s * 64 + a] = (short)f2bf((acc[ms][r] + bb) * EXPC);
            }
    } else if (which == 1) {
        short* Ob = Out + (size_t)bh * SLEN * 64;
#pragma unroll
        for (int ms = 0; ms < 2; ++ms)
#pragma unroll
            for (int r = 0; r < 16; ++r) {
                int s = sb + ms * 32 + (r & 3) + 8 * (r >> 2) + 4 * hi;
                Ob[(size_t)s * 64 + a] = (short)f2bf(acc[ms][r] + bb);
            }
    } else {
        short* Ob = Out + ((size_t)bh * 64 + a) * SLEN;
#pragma unroll
        for (int ms = 0; ms < 2; ++ms)
#pragma unroll
            for (int g = 0; g < 4; ++g) {
                int s = sb + ms * 32 + 8 * g + 4 * hi;
                ushort4 w;
                w.x = f2bf(acc[ms][4 * g + 0] + bb);
                w.y = f2bf(acc[ms][4 * g + 1] + bb);
                w.z = f2bf(acc[ms][4 * g + 2] + bb);
                w.w = f2bf(acc[ms][4 * g + 3] + bb);
                *(ushort4*)&Ob[s] = w;
            }
    }
}

// ---------------------------------------------------------------------------
// attn (R7 verified optimum: grid (8,16,4), q-heavy 256q x 512k, LDA=66
// conflict-free, single LDS buffer + reg prefetch, setprio on MFMA).
// ---------------------------------------------------------------------------
__global__ __launch_bounds__(256, 2) void attn_mfma(
    const short* __restrict__ Qb, const short* __restrict__ Kb,
    const short* __restrict__ Vtb, short* __restrict__ Op,
    float* __restrict__ lp)
{
    __shared__ short Ks[64 * LDA];
    __shared__ short Vs[64 * LDA];

    const int tid = threadIdx.x;
    const int wid = tid >> 6;
    const int lane = tid & 63;
    const int l31 = lane & 31;
    const int hi = lane >> 5;

    const int qt = blockIdx.x;
    const int bh = blockIdx.y;
    const int sp = blockIdx.z;

    const short* Qg = Qb + (size_t)bh * SLEN * 64;
    const short* Kg = Kb + (size_t)bh * SLEN * 64;
    const short* Vg = Vtb + (size_t)bh * 64 * SLEN;

    const int q0 = qt * 256 + wid * 64;

    short8 qf[2][4];
#pragma unroll
    for (int nt = 0; nt < 2; ++nt)
#pragma unroll
        for (int ks = 0; ks < 4; ++ks)
            qf[nt][ks] = *(const short8*)&Qg[(size_t)(q0 + nt * 32 + l31) * 64 + ks * 16 + hi * 8];

    f32x16 oacc[2][2];
    float lsum[2] = {0.f, 0.f};
#pragma unroll
    for (int nt = 0; nt < 2; ++nt)
#pragma unroll
        for (int dt = 0; dt < 2; ++dt)
#pragma unroll
            for (int r = 0; r < 16; ++r) oacc[nt][dt][r] = 0.f;

    const int srow = tid >> 2;
    const int sch = (tid & 3) * 16;
    const int kbase = sp * (SLEN / SPLIT);

    // prologue: stage tile 0 into registers
    short8 rk0 = *(const short8*)&Kg[(size_t)(kbase + srow) * 64 + sch];
    short8 rk1 = *(const short8*)&Kg[(size_t)(kbase + srow) * 64 + sch + 8];
    short8 rv0 = *(const short8*)&Vg[(size_t)srow * SLEN + kbase + sch];
    short8 rv1 = *(const short8*)&Vg[(size_t)srow * SLEN + kbase + sch + 8];

#pragma unroll 1
    for (int kt = 0; kt < 8; ++kt) {
        __syncthreads();
        *(short8*)&Ks[srow * LDA + sch]     = rk0;
        *(short8*)&Ks[srow * LDA + sch + 8] = rk1;
        *(short8*)&Vs[srow * LDA + sch]     = rv0;
        *(short8*)&Vs[srow * LDA + sch + 8] = rv1;
        __syncthreads();

        if (kt < 7) {
            const int k0n = kbase + (kt + 1) * 64;
            rk0 = *(const short8*)&Kg[(size_t)(k0n + srow) * 64 + sch];
            rk1 = *(const short8*)&Kg[(size_t)(k0n + srow) * 64 + sch + 8];
            rv0 = *(const short8*)&Vg[(size_t)srow * SLEN + k0n + sch];
            rv1 = *(const short8*)&Vg[(size_t)srow * SLEN + k0n + sch + 8];
        }

        short8 kf[2][4], vf[2][4];
#pragma unroll
        for (int mt = 0; mt < 2; ++mt)
#pragma unroll
            for (int ks = 0; ks < 4; ++ks)
                kf[mt][ks] = *(const short8*)&Ks[(mt * 32 + l31) * LDA + ks * 16 + hi * 8];
#pragma unroll
        for (int dt = 0; dt < 2; ++dt)
#pragma unroll
            for (int p = 0; p < 4; ++p)
                vf[dt][p] = *(const short8*)&Vs[(dt * 32 + l31) * LDA + p * 16 + hi * 8];

#pragma unroll
        for (int nt = 0; nt < 2; ++nt) {
            f32x16 sacc[2];
            __builtin_amdgcn_s_setprio(1);
#pragma unroll
            for (int mt = 0; mt < 2; ++mt) {
                f32x16 s;
#pragma unroll
                for (int r = 0; r < 16; ++r) s[r] = 0.f;
#pragma unroll
                for (int ks = 0; ks < 4; ++ks)
                    s = __builtin_amdgcn_mfma_f32_32x32x16_bf16(kf[mt][ks], qf[nt][ks], s, 0, 0, 0);
                sacc[mt] = s;
            }
            __builtin_amdgcn_s_setprio(0);

            // p = exp2(s); pack via v_perm truncation; VALU lsum on the SAME
            // truncated values (numerator/denominator rounding matched).
            int2 pk[2][4];
#pragma unroll
            for (int mt = 0; mt < 2; ++mt)
#pragma unroll
                for (int g = 0; g < 4; ++g) {
                    unsigned a0 = __float_as_uint(__builtin_amdgcn_exp2f(sacc[mt][4 * g + 0]));
                    unsigned a1 = __float_as_uint(__builtin_amdgcn_exp2f(sacc[mt][4 * g + 1]));
                    unsigned a2 = __float_as_uint(__builtin_amdgcn_exp2f(sacc[mt][4 * g + 2]));
                    unsigned a3 = __float_as_uint(__builtin_amdgcn_exp2f(sacc[mt][4 * g + 3]));
                    float t0 = __uint_as_float(a0 & 0xffff0000u);
                    float t1 = __uint_as_float(a1 & 0xffff0000u);
                    float t2 = __uint_as_float(a2 & 0xffff0000u);
                    float t3 = __uint_as_float(a3 & 0xffff0000u);
                    lsum[nt] += (t0 + t1) + (t2 + t3);
                    pk[mt][g].x = (int)__builtin_amdgcn_perm(a1, a0, 0x07060302u);
                    pk[mt][g].y = (int)__builtin_amdgcn_perm(a3, a2, 0x07060302u);
                }

            int2 xch[2][2];
#pragma unroll
            for (int mt = 0; mt < 2; ++mt)
#pragma unroll
                for (int h2 = 0; h2 < 2; ++h2) {
                    int2 v = hi ? pk[mt][2 * h2] : pk[mt][2 * h2 + 1];
                    xch[mt][h2].x = __shfl_xor(v.x, 32);
                    xch[mt][h2].y = __shfl_xor(v.y, 32);
                }

            __builtin_amdgcn_s_setprio(1);
#pragma unroll
            for (int p = 0; p < 4; ++p) {
                const int mt = p >> 1, h2 = p & 1;
                const int ga = 2 * h2, gb = 2 * h2 + 1;
                const int2 X = xch[mt][h2];
                union { int4 i; short8 s; } u;
                u.i.x = hi ? X.x : pk[mt][ga].x;
                u.i.y = hi ? X.y : pk[mt][ga].y;
                u.i.z = hi ? pk[mt][gb].x : X.x;
                u.i.w = hi ? pk[mt][gb].y : X.y;
#pragma unroll
                for (int dt = 0; dt < 2; ++dt)
                    oacc[nt][dt] = __builtin_amdgcn_mfma_f32_32x32x16_bf16(u.s, vf[dt][p], oacc[nt][dt], 0, 0, 0);
            }
            __builtin_amdgcn_s_setprio(0);
        }
    }

#pragma unroll
    for (int nt = 0; nt < 2; ++nt) {
        float lt = lsum[nt] + __shfl_xor(lsum[nt], 32);
        if (hi == 0)
            lp[((size_t)(sp * 16 + bh)) * SLEN + q0 + nt * 32 + l31] = lt;
#pragma unroll
        for (int dt = 0; dt < 2; ++dt) {
#pragma unroll
            for (int r = 0; r < 16; ++r) {
                int qrow = (r & 3) + 8 * (r >> 2) + 4 * hi;
                size_t addr = (((size_t)(sp * 16 + bh)) * SLEN + (q0 + nt * 32 + qrow)) * 64 + dt * 32 + l31;
                Op[addr] = (short)f2bf(oacc[nt][dt][r]);
            }
        }
    }
}

// ---------------------------------------------------------------------------
// Merge key-split partials -> hc bf16 [b,s, h*64+d] (verbatim R1/R7)
// ---------------------------------------------------------------------------
__global__ __launch_bounds__(256) void merge_k(
    const short* __restrict__ Op, const float* __restrict__ lp,
    short* __restrict__ hc)
{
    const int g = blockIdx.x * 256 + threadIdx.x;   // 512K threads
    const int d4 = g & 15;
    const int s = (g >> 4) & (SLEN - 1);
    const int bh = g >> 15;

    float o[4] = {0.f, 0.f, 0.f, 0.f};
    float ls = 0.f;
#pragma unroll
    for (int sp = 0; sp < SPLIT; ++sp) {
        const size_t base = (((size_t)(sp * 16 + bh)) * SLEN + s);
        ushort4 u4 = *(const ushort4*)&Op[base * 64 + d4 * 4];
        o[0] += bf2f((short)u4.x); o[1] += bf2f((short)u4.y);
        o[2] += bf2f((short)u4.z); o[3] += bf2f((short)u4.w);
        ls += lp[base];
    }
    const int b = bh >> 3, h = bh & 7;
    const float inv = 1.f / ls;
    ushort4 w;
    w.x = f2bf(o[0] * inv); w.y = f2bf(o[1] * inv);
    w.z = f2bf(o[2] * inv); w.w = f2bf(o[3] * inv);
    *(ushort4*)&hc[((size_t)(b * SLEN + s)) * DDIM + h * 64 + d4 * 4] = w;
}

// ---------------------------------------------------------------------------
// AddNorm on bf16 stream (verbatim R1/R7): xbf = LN(xbf + y) * g + b ; y fp32.
// ---------------------------------------------------------------------------
__global__ __launch_bounds__(256) void addnorm_bf(
    short* __restrict__ X, const float* __restrict__ Y,
    const float* __restrict__ g, const float* __restrict__ beta)
{
    const int lane = threadIdx.x & 63;
    const int t = blockIdx.x * 4 + (threadIdx.x >> 6);
    short* xr = X + (size_t)t * DDIM;
    const float* yr = Y + (size_t)t * DDIM;
    const int c0 = lane * 8;

    short8 x8 = *(const short8*)&xr[c0];
    float4 y0 = *(const float4*)&yr[c0];
    float4 y1 = *(const float4*)&yr[c0 + 4];
    float v[8];
    v[0] = bf2f(x8[0]) + y0.x; v[1] = bf2f(x8[1]) + y0.y;
    v[2] = bf2f(x8[2]) + y0.z; v[3] = bf2f(x8[3]) + y0.w;
    v[4] = bf2f(x8[4]) + y1.x; v[5] = bf2f(x8[5]) + y1.y;
    v[6] = bf2f(x8[6]) + y1.z; v[7] = bf2f(x8[7]) + y1.w;

    float s1 = 0.f, s2 = 0.f;
#pragma unroll
    for (int j = 0; j < 8; ++j) { s1 += v[j]; s2 += v[j] * v[j]; }
#pragma unroll
    for (int off = 1; off < 64; off <<= 1) {
        s1 += __shfl_xor(s1, off);
        s2 += __shfl_xor(s2, off);
    }
    float mean = s1 * (1.0f / DDIM);
    float var = s2 * (1.0f / DDIM) - mean * mean;
    float rstd = rsqrtf(var + 1e-5f);

    float4 ga = *(const float4*)&g[c0];
    float4 gb = *(const float4*)&g[c0 + 4];
    float4 ba = *(const float4*)&beta[c0];
    float4 bb = *(const float4*)&beta[c0 + 4];
    float gg[8] = {ga.x, ga.y, ga.z, ga.w, gb.x, gb.y, gb.z, gb.w};
    float bt[8] = {ba.x, ba.y, ba.z, ba.w, bb.x, bb.y, bb.z, bb.w};

    short8 o8;
#pragma unroll
    for (int j = 0; j < 8; ++j)
        o8[j] = (short)f2bf((v[j] - mean) * rstd * gg[j] + bt[j]);
    *(short8*)&xr[c0] = o8;
}

// ---------------------------------------------------------------------------
// Workspace (MiB), overlays lifetime-checked (R1/R7 layout):
//   [ 0, 4)  xbf            (alive whole run)
//   [ 4, 8)  Qbuf | hcbf    (Q dead after attn; hc dead after Wo)
//   [ 8,12)  Kbuf
//   [12,16)  Vtbuf
//   [16,32)  Opart (attn->merge) | y fp32 [16,24) | hidbf [24,28)
//   [32,32.5) lpart
//   [33,39.25) weights bf16
// ---------------------------------------------------------------------------
extern "C" void kernel_launch(void* const* d_in, const int* in_sizes, int n_in,
                              void* d_out, int out_size, void* d_ws, size_t ws_size,
                              hipStream_t stream)
{
    (void)in_sizes; (void)n_in; (void)out_size; (void)ws_size;
    const float* x   = (const float*)d_in[0];
    const float* Wq  = (const float*)d_in[1];
    const float* bq  = (const float*)d_in[2];
    const float* Wk  = (const float*)d_in[3];
    const float* bk  = (const float*)d_in[4];
    const float* Wv  = (const float*)d_in[5];
    const float* bv  = (const float*)d_in[6];
    const float* Wo  = (const float*)d_in[7];
    const float* bo  = (const float*)d_in[8];
    const float* g1  = (const float*)d_in[9];
    const float* be1 = (const float*)d_in[10];
    const float* W1  = (const float*)d_in[11];
    const float* b1  = (const float*)d_in[12];
    const float* W2  = (const float*)d_in[13];
    const float* b2  = (const float*)d_in[14];
    const float* g2  = (const float*)d_in[15];
    const float* be2 = (const float*)d_in[16];
    const float* Wp  = (const float*)d_in[17];
    const float* bp  = (const float*)d_in[18];

    char* wsb = (char*)d_ws;
    const size_t MB = 1024 * 1024;
    short* xbf   = (short*)(wsb + 0);
    short* Qbuf  = (short*)(wsb + 4 * MB);
    short* Kbuf  = (short*)(wsb + 8 * MB);
    short* Vtbuf = (short*)(wsb + 12 * MB);
    short* Opart = (short*)(wsb + 16 * MB);
    float* y     = (float*)(wsb + 16 * MB);   // overlay (disjoint lifetime)
    short* hidbf = (short*)(wsb + 24 * MB);   // overlay (disjoint lifetime)
    float* lpart = (float*)(wsb + 32 * MB);
    short* hcbf  = Qbuf;                       // overlay
    short* Wqt   = (short*)(wsb + 33 * MB);
    short* Wkt   = (short*)(wsb + 34 * MB);
    short* Wvt   = (short*)(wsb + 35 * MB);
    short* Wot   = (short*)(wsb + 36 * MB);
    short* W1t   = (short*)(wsb + 37 * MB);
    short* W2t   = (short*)(wsb + 38 * MB);
    short* Wpt   = (short*)(wsb + 39 * MB);

    prep_k<<<1056, 256, 0, stream>>>(Wq, Wk, Wv, Wo, W1, W2, Wp, x,
                                     Wqt, Wkt, Wvt, Wot, W1t, W2t, Wpt, xbf);

    for (int i = 0; i < 2; ++i) {
        const size_t wOff = (size_t)i * 262144;
        qkv_bf<<<dim3(24, 32), 256, 0, stream>>>(
            xbf, Wqt + wOff, Wkt + wOff, Wvt + wOff,
            bq + i * 512, bk + i * 512, bv + i * 512,
            Qbuf, Kbuf, Vtbuf);
        attn_mfma<<<dim3(8, 16, SPLIT), 256, 0, stream>>>(Qbuf, Kbuf, Vtbuf, Opart, lpart);
        merge_k<<<2048, 256, 0, stream>>>(Opart, lpart, hcbf);
        gemm_bf<<<dim3(8, 64), 256, 0, stream>>>(
            hcbf, Wot + wOff, bo + i * 512, y, MDIM, DDIM, DDIM, 0);
        addnorm_bf<<<1024, 256, 0, stream>>>(xbf, y, g1 + i * 512, be1 + i * 512);
        gemm_bf<<<dim3(8, 64), 256, 0, stream>>>(
            xbf, W1t + wOff, b1 + i * 512, hidbf, MDIM, DDIM, DDIM, 3);
        gemm_bf<<<dim3(8, 64), 256, 0, stream>>>(
            hidbf, W2t + wOff, b2 + i * 512, y, MDIM, DDIM, DDIM, 0);
        addnorm_bf<<<1024, 256, 0, stream>>>(xbf, y, g2 + i * 512, be2 + i * 512);
    }
    gemm_bf<<<dim3(4, 64), 256, 0, stream>>>(
        xbf, Wpt, bp, (float*)d_out, MDIM, TDIM, DDIM, 0);
}